// Round 12
// baseline (281.351 us; speedup 1.0000x reference)
//
#include <hip/hip_runtime.h>

// 2-layer GCN. R12: edges counting-sorted by dst-GROUP (dst>>6, 64 nodes/group);
// aggregation = one WAVE per group, lane = node: stage (key,value) tiles into
// per-wave LDS (coalesced + deep-MLP gathers), broadcast-scan with register
// accumulation. ZERO LDS atomics in aggregation (R3..R11's invariant 40.6us
// agg1 = 8.4 cyc/edge = 2 ds_atomic/edge at ~4cy/lane-op on the per-CU DS
// pipe). Fusions: deg+px, agg1+MLP, agg2+out. No partial arrays.

#define NBMAX 2048
#define CHUNK 4096
#define NCHP 640         // max chunks (e <= 2.62M edges)
#define GBITS 6
#define GMASK 63

// ---------------- block-wide exclusive scan (1024 threads) ----------------

__device__ __forceinline__ int block_scan_excl(int v, int tid, int* wtot /*LDS[17]*/) {
    int lane = tid & 63, w = tid >> 6;
    int inc = v;
#pragma unroll
    for (int d = 1; d < 64; d <<= 1) {
        int u = __shfl_up(inc, d);
        if (lane >= d) inc += u;
    }
    if (lane == 63) wtot[w] = inc;
    __syncthreads();
    if (w == 0) {
        int t = (lane < 16) ? wtot[lane] : 0;
#pragma unroll
        for (int d = 1; d < 16; d <<= 1) {
            int u = __shfl_up(t, d);
            if (lane >= d) t += u;
        }
        if (lane < 16) wtot[lane] = t;
        if (lane == 15) wtot[16] = t;   // grand total
    }
    __syncthreads();
    int base = (w > 0) ? wtot[w - 1] : 0;
    return base + inc - v;   // exclusive
}

// ---------------- bucketing: count -> scanA -> scanB -> scatter ------------

__global__ void k_cnt(const int* __restrict__ src, const int* __restrict__ dst,
                      int* __restrict__ cntT, int e, int NB) {
    __shared__ int h[NBMAX];
    for (int t = threadIdx.x; t < NB; t += blockDim.x) h[t] = 0;
    __syncthreads();
    int c0 = blockIdx.x * CHUNK, c1 = min(c0 + CHUNK, e);
    int len = c1 - c0, lq = len >> 2;
    const int4* d4 = (const int4*)(dst + c0);
    for (int j = threadIdx.x; j < lq; j += blockDim.x) {
        int4 dv = d4[j];
        atomicAdd(&h[dv.x >> GBITS], 1);
        atomicAdd(&h[dv.y >> GBITS], 1);
        atomicAdd(&h[dv.z >> GBITS], 1);
        atomicAdd(&h[dv.w >> GBITS], 1);
    }
    if (threadIdx.x == 0)
        for (int i = lq * 4; i < len; ++i) atomicAdd(&h[dst[c0 + i] >> GBITS], 1);
    __syncthreads();
    for (int t = threadIdx.x; t < NB; t += blockDim.x)
        cntT[blockIdx.x * NBMAX + t] = h[t];
}

// one block PER BIN: IN-PLACE exclusive scan of the bin's column of cntT
__global__ __launch_bounds__(1024)
void k_scanA(int* __restrict__ cntT, int* __restrict__ tot, int NCH) {
    __shared__ int wtot[17];
    int bin = blockIdx.x, tid = threadIdx.x;
    int v = (tid < NCH) ? cntT[tid * NBMAX + bin] : 0;
    int ex = block_scan_excl(v, tid, wtot);
    if (tid < NCH) cntT[tid * NBMAX + bin] = ex;
    if (tid == 0) tot[bin] = wtot[16];
}

// one block: pair-scan (2 bins/thread) of bin totals -> gbin (exact, no pad)
__global__ __launch_bounds__(1024)
void k_scanB(const int* __restrict__ tot, int* __restrict__ gbin, int NB) {
    __shared__ int wtot[17];
    int tid = threadIdx.x;
    int b0 = 2 * tid, b1 = b0 + 1;
    int t0 = (b0 < NB) ? tot[b0] : 0;
    int t1 = (b1 < NB) ? tot[b1] : 0;
    int ps = block_scan_excl(t0 + t1, tid, wtot);
    if (b0 < NB) gbin[b0] = ps;
    if (b1 < NB) gbin[b1] = ps + t0;
}

// LDS counting-sort per chunk into groups; pair-scan lofs; sorted flush
__global__ __launch_bounds__(1024)
void k_bscatter(const int* __restrict__ src, const int* __restrict__ dst,
                const int* __restrict__ ofsT, const int* __restrict__ tot,
                const int* __restrict__ gbin, unsigned* __restrict__ packed,
                int e, int NB, int NCH) {
    __shared__ int curx[NBMAX], gba[NBMAX];   // 16 KB
    __shared__ unsigned sbuf[CHUNK];          // 16 KB
    __shared__ int dest[CHUNK];               // 16 KB
    __shared__ int wtot[17];
    int blk = blockIdx.x, tid = threadIdx.x;
    int c0 = blk * CHUNK, c1 = min(c0 + CHUNK, e);
    int len = c1 - c0, lq = len >> 2;
    int b0 = 2 * tid, b1 = b0 + 1;
    int cur0 = 0, cur1 = 0, h0 = 0, h1 = 0;
    if (b0 < NB) {
        cur0 = ofsT[blk * NBMAX + b0];
        int nxt = (blk + 1 < NCH) ? ofsT[(blk + 1) * NBMAX + b0] : tot[b0];
        h0 = nxt - cur0;
    }
    if (b1 < NB) {
        cur1 = ofsT[blk * NBMAX + b1];
        int nxt = (blk + 1 < NCH) ? ofsT[(blk + 1) * NBMAX + b1] : tot[b1];
        h1 = nxt - cur1;
    }
    int lo = block_scan_excl(h0 + h1, tid, wtot);
    if (b0 < NB) { curx[b0] = lo;      gba[b0] = gbin[b0] + cur0 - lo; }
    if (b1 < NB) { curx[b1] = lo + h0; gba[b1] = gbin[b1] + cur1 - (lo + h0); }
    __syncthreads();
    const int4* d4 = (const int4*)(dst + c0);
    const int4* s4 = (const int4*)(src + c0);
    for (int j = tid; j < lq; j += blockDim.x) {
        int4 dv = d4[j], sv = s4[j];
        {
            int b = dv.x >> GBITS; int sl = atomicAdd(&curx[b], 1);
            sbuf[sl] = ((unsigned)sv.x << GBITS) | (unsigned)(dv.x & GMASK);
            dest[sl] = gba[b] + sl;
        }
        {
            int b = dv.y >> GBITS; int sl = atomicAdd(&curx[b], 1);
            sbuf[sl] = ((unsigned)sv.y << GBITS) | (unsigned)(dv.y & GMASK);
            dest[sl] = gba[b] + sl;
        }
        {
            int b = dv.z >> GBITS; int sl = atomicAdd(&curx[b], 1);
            sbuf[sl] = ((unsigned)sv.z << GBITS) | (unsigned)(dv.z & GMASK);
            dest[sl] = gba[b] + sl;
        }
        {
            int b = dv.w >> GBITS; int sl = atomicAdd(&curx[b], 1);
            sbuf[sl] = ((unsigned)sv.w << GBITS) | (unsigned)(dv.w & GMASK);
            dest[sl] = gba[b] + sl;
        }
    }
    if (tid == 0)
        for (int i = lq * 4; i < len; ++i) {
            int d = dst[c0 + i], sx = src[c0 + i];
            int b = d >> GBITS; int sl = atomicAdd(&curx[b], 1);
            sbuf[sl] = ((unsigned)sx << GBITS) | (unsigned)(d & GMASK);
            dest[sl] = gba[b] + sl;
        }
    __syncthreads();
    for (int t = tid; t < len; t += blockDim.x)
        packed[dest[t]] = sbuf[t];
}

// ---------------- wave-per-group aggregation (no atomics) ----------------
// 4 waves/block, wave w owns group g: lane = node (g<<6)+lane.

#define WPB 4

// deg (match count) + dinv + px, fused
__global__ __launch_bounds__(256)
void k_degpx(const unsigned* __restrict__ packed, const int* __restrict__ gbin,
             const int* __restrict__ tot, const float2* __restrict__ x,
             float* __restrict__ dinv, float2* __restrict__ px, int n, int NB) {
    __shared__ int keys[WPB][1024];   // 16 KB
    __shared__ int glen[WPB];
    int tid = threadIdx.x, wid = tid >> 6, lane = tid & 63;
    int g = blockIdx.x * WPB + wid;
    int gs = 0, len = 0;
    if (g < NB) { gs = gbin[g]; len = tot[g]; }
    if (lane == 0) glen[wid] = len;
    __syncthreads();
    int mx = max(max(glen[0], glen[1]), max(glen[2], glen[3]));
    int ntiles = (mx + 1023) >> 10;
    int cnt = 0;
    for (int t = 0; t < ntiles; ++t) {
        int t0 = t << 10;
        int tlen = min(1024, len - t0);
        for (int k = lane; k < tlen; k += 64) keys[wid][k] = (int)packed[gs + t0 + k];
        __syncthreads();
#pragma unroll 4
        for (int k = 0; k < tlen; ++k) cnt += ((keys[wid][k] & GMASK) == lane);
        __syncthreads();
    }
    int i = (g << GBITS) + lane;
    if (g < NB && i < n) {
        float d = rsqrtf((float)(1 + cnt));   // self-loop
        dinv[i] = d;
        float2 xv = x[i];
        px[i] = make_float2(d * xv.x, d * xv.y);
    }
}

// layer-1 aggregation + node MLP, fused. Tile entry: float4(vx, vy, key, -)
__global__ __launch_bounds__(256)
void k_gather1(const unsigned* __restrict__ packed, const int* __restrict__ gbin,
               const int* __restrict__ tot, const float2* __restrict__ px,
               const float* __restrict__ dinv,
               const float* __restrict__ W1, const float* __restrict__ b1,
               const float* __restrict__ W2, float* __restrict__ s, int n, int NB) {
    __shared__ float4 vals[WPB][512];   // 32 KB
    __shared__ int glen[WPB];
    int tid = threadIdx.x, wid = tid >> 6, lane = tid & 63;
    int g = blockIdx.x * WPB + wid;
    int gs = 0, len = 0;
    if (g < NB) { gs = gbin[g]; len = tot[g]; }
    if (lane == 0) glen[wid] = len;
    __syncthreads();
    int mx = max(max(glen[0], glen[1]), max(glen[2], glen[3]));
    int ntiles = (mx + 511) >> 9;
    float ax = 0.f, ay = 0.f;
    for (int t = 0; t < ntiles; ++t) {
        int t0 = t << 9;
        int tlen = min(512, len - t0);
        for (int k = lane; k < tlen; k += 64) {
            unsigned u = packed[gs + t0 + k];
            float2 v = px[u >> GBITS];
            vals[wid][k] = make_float4(v.x, v.y, __int_as_float((int)(u & GMASK)), 0.f);
        }
        __syncthreads();
#pragma unroll 4
        for (int k = 0; k < tlen; ++k) {
            float4 q = vals[wid][k];
            if (__float_as_int(q.z) == lane) { ax += q.x; ay += q.y; }
        }
        __syncthreads();
    }
    int i = (g << GBITS) + lane;
    if (g < NB && i < n) {
        float2 v = px[i];           // self-loop
        ax += v.x; ay += v.y;
        float d = dinv[i];
        float dot = 0.f;
#pragma unroll
        for (int j = 0; j < 32; ++j) {
            float a2 = fmaf(ax, W1[j], ay * W1[32 + j]);
            float hh = fmaxf(fmaf(d, a2, b1[j]), 0.f);
            dot = fmaf(hh, W2[j], dot);
        }
        s[i] = d * dot;
    }
}

// layer-2 aggregation + output, fused. Tile entry: int2(key, bits(sval))
__global__ __launch_bounds__(256)
void k_gather2(const unsigned* __restrict__ packed, const int* __restrict__ gbin,
               const int* __restrict__ tot, const float* __restrict__ s,
               const float* __restrict__ dinv, const float* __restrict__ b2,
               float* __restrict__ out, int n, int NB) {
    __shared__ int2 kv[WPB][1024];   // 32 KB
    __shared__ int glen[WPB];
    int tid = threadIdx.x, wid = tid >> 6, lane = tid & 63;
    int g = blockIdx.x * WPB + wid;
    int gs = 0, len = 0;
    if (g < NB) { gs = gbin[g]; len = tot[g]; }
    if (lane == 0) glen[wid] = len;
    __syncthreads();
    int mx = max(max(glen[0], glen[1]), max(glen[2], glen[3]));
    int ntiles = (mx + 1023) >> 10;
    float a = 0.f;
    for (int t = 0; t < ntiles; ++t) {
        int t0 = t << 10;
        int tlen = min(1024, len - t0);
        for (int k = lane; k < tlen; k += 64) {
            unsigned u = packed[gs + t0 + k];
            kv[wid][k] = make_int2((int)(u & GMASK), __float_as_int(s[u >> GBITS]));
        }
        __syncthreads();
#pragma unroll 4
        for (int k = 0; k < tlen; ++k) {
            int2 q = kv[wid][k];
            if (q.x == lane) a += __int_as_float(q.y);
        }
        __syncthreads();
    }
    int i = (g << GBITS) + lane;
    if (g < NB && i < n)
        out[i] = dinv[i] * (s[i] + a) + b2[0];
}

// ---------------- fallback path (round-2 style) ----------------

__global__ void f_zero(int* __restrict__ ideg, float2* __restrict__ P, int n) {
    int i = blockIdx.x * blockDim.x + threadIdx.x;
    if (i < n) { ideg[i] = 0; P[i] = make_float2(0.f, 0.f); }
}
__global__ void f_count(const int* __restrict__ dst, int* __restrict__ ideg, int e) {
    int i = blockIdx.x * blockDim.x + threadIdx.x;
    if (i < e) atomicAdd(&ideg[dst[i]], 1);
}
__global__ void f_px(const float2* __restrict__ x, const int* __restrict__ ideg,
                     float* __restrict__ dinv, float2* __restrict__ px, int n) {
    int i = blockIdx.x * blockDim.x + threadIdx.x;
    if (i >= n) return;
    float d = rsqrtf((float)(1 + ideg[i]));
    dinv[i] = d;
    float2 xv = x[i];
    px[i] = make_float2(d * xv.x, d * xv.y);
}
__global__ void f_scatter_px(const int* __restrict__ src, const int* __restrict__ dst,
                             const float2* __restrict__ px, float* __restrict__ Pf, int e) {
    int i = blockIdx.x * blockDim.x + threadIdx.x;
    if (i >= e) return;
    int sidx = src[i], d = dst[i];
    float2 v = px[sidx];
    atomicAdd(&Pf[2 * d], v.x);
    atomicAdd(&Pf[2 * d + 1], v.y);
}
__global__ void f_node(const float2* __restrict__ px, const float2* __restrict__ P,
                       const float* __restrict__ dinv,
                       const float* __restrict__ W1, const float* __restrict__ b1,
                       const float* __restrict__ W2,
                       float* __restrict__ s, float* __restrict__ S, int n) {
    int i = blockIdx.x * blockDim.x + threadIdx.x;
    if (i >= n) return;
    float d = dinv[i];
    float2 v = px[i], p = P[i];
    float ax = v.x + p.x, ay = v.y + p.y;
    float dot = 0.f;
#pragma unroll
    for (int j = 0; j < 32; ++j) {
        float acc = fmaf(ax, W1[j], ay * W1[32 + j]);
        float h = fmaxf(fmaf(d, acc, b1[j]), 0.f);
        dot = fmaf(h, W2[j], dot);
    }
    float sv = d * dot;
    s[i] = sv;
    S[i] = sv;
}
__global__ void f_scatter_s(const int* __restrict__ src, const int* __restrict__ dst,
                            const float* __restrict__ s, float* __restrict__ S, int e) {
    int i = blockIdx.x * blockDim.x + threadIdx.x;
    if (i < e) atomicAdd(&S[dst[i]], s[src[i]]);
}
__global__ void f_out(const float* __restrict__ S, const float* __restrict__ dinv,
                      const float* __restrict__ b2, float* __restrict__ out, int n) {
    int i = blockIdx.x * blockDim.x + threadIdx.x;
    if (i < n) out[i] = dinv[i] * S[i] + b2[0];
}

// ---------------- launch ----------------

extern "C" void kernel_launch(void* const* d_in, const int* in_sizes, int n_in,
                              void* d_out, int out_size, void* d_ws, size_t ws_size,
                              hipStream_t stream) {
    const float* x  = (const float*)d_in[0];
    const int*   ei = (const int*)d_in[1];
    const float* W1 = (const float*)d_in[2];
    const float* b1 = (const float*)d_in[3];
    const float* W2 = (const float*)d_in[4];
    const float* b2 = (const float*)d_in[5];
    float* out = (float*)d_out;

    int n = in_sizes[0] / 2;   // 100000
    int e = in_sizes[1] / 2;   // 2560000
    const int* src = ei;
    const int* dst = ei + e;
    int NB  = (n + GMASK) >> GBITS;          // 1563 dst-groups of 64
    int NCH = (e + CHUNK - 1) / CHUNK;       // 625 chunks

    char* ws = (char*)d_ws;
    auto align = [](size_t v) { return (v + 255) & ~(size_t)255; };
    size_t off = 0;
    float*  dinv = (float*) (ws + off); off = align(off + (size_t)n * 4);
    float2* px   = (float2*)(ws + off); off = align(off + (size_t)n * 8);
    float*  s    = (float*) (ws + off); off = align(off + (size_t)n * 4);
    int*    gbin = (int*)(ws + off); off = align(off + NBMAX * 4);
    int*    tot  = (int*)(ws + off); off = align(off + NBMAX * 4);
    int*    cntT = (int*)(ws + off); off = align(off + (size_t)NCHP * NBMAX * 4);
    unsigned* packed = (unsigned*)(ws + off);
    size_t need = off + (size_t)e * 4;

    // fallback scratch aliases (reuse same region; fallback needs ~2.4MB)
    int*    f_ideg = (int*)cntT;
    float2* f_P    = (float2*)(cntT + NBMAX * 16);
    float*  f_S    = (float*)(f_P + n);

    const int B = 256;
    int gn = (n + B - 1) / B, ge = (e + B - 1) / B;

    bool fast = (need <= ws_size) && (NB <= NBMAX) && (NCH <= NCHP) &&
                (n <= (1 << (31 - GBITS - 6)));   // src<<6 fits 31 bits

    if (fast) {
        int gagg = (NB + WPB - 1) / WPB;   // 391 blocks
        k_cnt     <<<NCH, B, 0, stream>>>(src, dst, cntT, e, NB);
        k_scanA   <<<NB, 1024, 0, stream>>>(cntT, tot, NCH);
        k_scanB   <<<1, 1024, 0, stream>>>(tot, gbin, NB);
        k_bscatter<<<NCH, 1024, 0, stream>>>(src, dst, cntT, tot, gbin, packed, e, NB, NCH);
        k_degpx   <<<gagg, B, 0, stream>>>(packed, gbin, tot, (const float2*)x,
                                           dinv, px, n, NB);
        k_gather1 <<<gagg, B, 0, stream>>>(packed, gbin, tot, px, dinv,
                                           W1, b1, W2, s, n, NB);
        k_gather2 <<<gagg, B, 0, stream>>>(packed, gbin, tot, s, dinv, b2, out, n, NB);
    } else {
        f_zero      <<<gn, B, 0, stream>>>(f_ideg, f_P, n);
        f_count     <<<ge, B, 0, stream>>>(dst, f_ideg, e);
        f_px        <<<gn, B, 0, stream>>>((const float2*)x, f_ideg, dinv, px, n);
        f_scatter_px<<<ge, B, 0, stream>>>(src, dst, px, (float*)f_P, e);
        f_node      <<<gn, B, 0, stream>>>(px, f_P, dinv, W1, b1, W2, s, f_S, n);
        f_scatter_s <<<ge, B, 0, stream>>>(src, dst, s, f_S, e);
        f_out       <<<gn, B, 0, stream>>>(f_S, dinv, b2, out, n);
    }
}

// Round 13
// 137.982 us; speedup vs baseline: 2.0391x; 2.0391x over previous
//
#include <hip/hip_runtime.h>

// 2-layer GCN, rank-2 factorization + 2-level (dst>>12, src>>11) bucketing +
// LDS aggregation. R13: agg kernels stage each bin's 2048-node src window
// into LDS (coalesced) and gather from LDS — replaces the per-edge divergent
// VMEM gather (~16cy addr-processing) with a ~3cy LDS read. k_deg unchanged
// as the no-gather control. Pipeline otherwise = R11 (110us).

#define CSTR 1280        // cntT row stride (>= NB)
#define NRMAX 32
#define AGG_BLKS 16
#define CHUNK 4096
#define NCHP 640         // max chunks (e <= 2.62M edges)
#define DBITS 12
#define DMASK 4095
#define SBITS 11
#define SMASK 2047
#define NOEDGE 0xFFFFFFFFu

// ---------------- block-wide exclusive scan (1024 threads) ----------------

__device__ __forceinline__ int block_scan_excl(int v, int tid, int* wtot /*LDS[17]*/) {
    int lane = tid & 63, w = tid >> 6;
    int inc = v;
#pragma unroll
    for (int d = 1; d < 64; d <<= 1) {
        int u = __shfl_up(inc, d);
        if (lane >= d) inc += u;
    }
    if (lane == 63) wtot[w] = inc;
    __syncthreads();
    if (w == 0) {
        int t = (lane < 16) ? wtot[lane] : 0;
#pragma unroll
        for (int d = 1; d < 16; d <<= 1) {
            int u = __shfl_up(t, d);
            if (lane >= d) t += u;
        }
        if (lane < 16) wtot[lane] = t;
        if (lane == 15) wtot[16] = t;   // grand total
    }
    __syncthreads();
    int base = (w > 0) ? wtot[w - 1] : 0;
    return base + inc - v;   // exclusive
}

// ---------------- node-local kernels ----------------

__global__ void k_px(const float2* __restrict__ x, const int* __restrict__ pdeg,
                     float* __restrict__ dinv, float2* __restrict__ px, int n) {
    int i = blockIdx.x * blockDim.x + threadIdx.x;
    if (i >= n) return;
    int deg = 1;  // self-loop
#pragma unroll
    for (int b = 0; b < AGG_BLKS; ++b) deg += pdeg[b * n + i];
    float d = rsqrtf((float)deg);
    dinv[i] = d;
    float2 xv = x[i];
    px[i] = make_float2(d * xv.x, d * xv.y);
}

__global__ void k_node(const float2* __restrict__ px, const float2* __restrict__ pP,
                       const float* __restrict__ dinv,
                       const float* __restrict__ W1, const float* __restrict__ b1,
                       const float* __restrict__ W2, float* __restrict__ s, int n) {
    int i = blockIdx.x * blockDim.x + threadIdx.x;
    if (i >= n) return;
    float2 v = px[i];
    float ax = v.x, ay = v.y;
#pragma unroll
    for (int b = 0; b < AGG_BLKS; ++b) {
        float2 p = pP[b * n + i];
        ax += p.x; ay += p.y;
    }
    float d = dinv[i];
    float dot = 0.f;
#pragma unroll
    for (int j = 0; j < 32; ++j) {
        float acc = fmaf(ax, W1[j], ay * W1[32 + j]);
        float h = fmaxf(fmaf(d, acc, b1[j]), 0.f);
        dot = fmaf(h, W2[j], dot);
    }
    s[i] = d * dot;
}

__global__ void k_out(const float* __restrict__ s, const float* __restrict__ ps,
                      const float* __restrict__ dinv, const float* __restrict__ b2,
                      float* __restrict__ out, int n) {
    int i = blockIdx.x * blockDim.x + threadIdx.x;
    if (i >= n) return;
    float acc = s[i];  // self-loop
#pragma unroll
    for (int b = 0; b < AGG_BLKS; ++b) acc += ps[b * n + i];
    out[i] = dinv[i] * acc + b2[0];
}

// ---------------- bucketing: count -> scanA -> scanB -> scatter ------------

__global__ void k_cnt(const int* __restrict__ src, const int* __restrict__ dst,
                      int* __restrict__ cntT, int e, int NS, int NB) {
    __shared__ int h[CSTR];
    for (int t = threadIdx.x; t < NB; t += blockDim.x) h[t] = 0;
    __syncthreads();
    int c0 = blockIdx.x * CHUNK, c1 = min(c0 + CHUNK, e);
    int len = c1 - c0, lq = len >> 2;
    const int4* d4 = (const int4*)(dst + c0);
    const int4* s4 = (const int4*)(src + c0);
    for (int j = threadIdx.x; j < lq; j += blockDim.x) {
        int4 dv = d4[j], sv = s4[j];
        atomicAdd(&h[(dv.x >> DBITS) * NS + (sv.x >> SBITS)], 1);
        atomicAdd(&h[(dv.y >> DBITS) * NS + (sv.y >> SBITS)], 1);
        atomicAdd(&h[(dv.z >> DBITS) * NS + (sv.z >> SBITS)], 1);
        atomicAdd(&h[(dv.w >> DBITS) * NS + (sv.w >> SBITS)], 1);
    }
    if (threadIdx.x == 0)
        for (int i = lq * 4; i < len; ++i)
            atomicAdd(&h[(dst[c0 + i] >> DBITS) * NS + (src[c0 + i] >> SBITS)], 1);
    __syncthreads();
    for (int t = threadIdx.x; t < NB; t += blockDim.x)
        cntT[blockIdx.x * CSTR + t] = h[t];
}

// one block PER BIN: IN-PLACE exclusive scan of the bin's column of cntT
__global__ __launch_bounds__(1024)
void k_scanA(int* __restrict__ cntT, int* __restrict__ tot, int NCH) {
    __shared__ int wtot[17];
    int bin = blockIdx.x, tid = threadIdx.x;
    int v = (tid < NCH) ? cntT[tid * CSTR + bin] : 0;
    int ex = block_scan_excl(v, tid, wtot);
    if (tid < NCH) cntT[tid * CSTR + bin] = ex;
    if (tid == 0) tot[bin] = wtot[16];
}

// one block: pair-scan of padded bin totals -> gbin, region table, sentinels
__global__ __launch_bounds__(1024)
void k_scanB(const int* __restrict__ tot, int* __restrict__ gbin,
             int* __restrict__ rbase, int* __restrict__ rlenp,
             unsigned* __restrict__ packed, int NB, int NS, int NR) {
    __shared__ int wtot[17];
    __shared__ int gball[2048];
    int tid = threadIdx.x;
    int b0 = 2 * tid, b1 = b0 + 1;
    int t0 = (b0 < NB) ? tot[b0] : 0;
    int t1 = (b1 < NB) ? tot[b1] : 0;
    int p0 = (t0 + 3) & ~3, p1 = (t1 + 3) & ~3;
    int ps = block_scan_excl(p0 + p1, tid, wtot);
    int total = wtot[16];
    if (b0 < NB) {
        gbin[b0] = ps; gball[b0] = ps;
        for (int k = t0; k < p0; ++k) packed[ps + k] = NOEDGE;
    }
    if (b1 < NB) {
        int base1 = ps + p0;
        gbin[b1] = base1; gball[b1] = base1;
        for (int k = t1; k < p1; ++k) packed[base1 + k] = NOEDGE;
    }
    __syncthreads();
    if (tid < NR) {
        int base = gball[tid * NS];
        int nxt = (tid + 1 < NR) ? gball[(tid + 1) * NS] : total;
        rbase[tid] = base;
        rlenp[tid] = nxt - base;   // multiple of 4
    }
}

// LDS counting-sort per chunk; pair handling; sorted flush via dest array
__global__ __launch_bounds__(1024)
void k_bscatter(const int* __restrict__ src, const int* __restrict__ dst,
                const int* __restrict__ ofsT, const int* __restrict__ tot,
                const int* __restrict__ gbin, unsigned* __restrict__ packed,
                int e, int NS, int NB, int NCH) {
    __shared__ int curx[CSTR], gba[CSTR];     // 10.2 KB
    __shared__ unsigned sbuf[CHUNK];          // 16 KB
    __shared__ int dest[CHUNK];               // 16 KB
    __shared__ int wtot[17];
    int blk = blockIdx.x, tid = threadIdx.x;
    int c0 = blk * CHUNK, c1 = min(c0 + CHUNK, e);
    int len = c1 - c0, lq = len >> 2;
    int b0 = 2 * tid, b1 = b0 + 1;
    int cur0 = 0, cur1 = 0, h0 = 0, h1 = 0;
    if (b0 < NB) {
        cur0 = ofsT[blk * CSTR + b0];
        int nxt = (blk + 1 < NCH) ? ofsT[(blk + 1) * CSTR + b0] : tot[b0];
        h0 = nxt - cur0;
    }
    if (b1 < NB) {
        cur1 = ofsT[blk * CSTR + b1];
        int nxt = (blk + 1 < NCH) ? ofsT[(blk + 1) * CSTR + b1] : tot[b1];
        h1 = nxt - cur1;
    }
    int lo = block_scan_excl(h0 + h1, tid, wtot);
    if (b0 < NB) { curx[b0] = lo;      gba[b0] = gbin[b0] + cur0 - lo; }
    if (b1 < NB) { curx[b1] = lo + h0; gba[b1] = gbin[b1] + cur1 - (lo + h0); }
    __syncthreads();
    const int4* d4 = (const int4*)(dst + c0);
    const int4* s4 = (const int4*)(src + c0);
    for (int j = tid; j < lq; j += blockDim.x) {
        int4 dv = d4[j], sv = s4[j];
        {
            int b = (dv.x >> DBITS) * NS + (sv.x >> SBITS);
            int sl = atomicAdd(&curx[b], 1);
            sbuf[sl] = ((unsigned)(sv.x & SMASK) << DBITS) | (unsigned)(dv.x & DMASK);
            dest[sl] = gba[b] + sl;
        }
        {
            int b = (dv.y >> DBITS) * NS + (sv.y >> SBITS);
            int sl = atomicAdd(&curx[b], 1);
            sbuf[sl] = ((unsigned)(sv.y & SMASK) << DBITS) | (unsigned)(dv.y & DMASK);
            dest[sl] = gba[b] + sl;
        }
        {
            int b = (dv.z >> DBITS) * NS + (sv.z >> SBITS);
            int sl = atomicAdd(&curx[b], 1);
            sbuf[sl] = ((unsigned)(sv.z & SMASK) << DBITS) | (unsigned)(dv.z & DMASK);
            dest[sl] = gba[b] + sl;
        }
        {
            int b = (dv.w >> DBITS) * NS + (sv.w >> SBITS);
            int sl = atomicAdd(&curx[b], 1);
            sbuf[sl] = ((unsigned)(sv.w & SMASK) << DBITS) | (unsigned)(dv.w & DMASK);
            dest[sl] = gba[b] + sl;
        }
    }
    if (tid == 0)
        for (int i = lq * 4; i < len; ++i) {
            int d = dst[c0 + i], sx = src[c0 + i];
            int b = (d >> DBITS) * NS + (sx >> SBITS);
            int sl = atomicAdd(&curx[b], 1);
            sbuf[sl] = ((unsigned)(sx & SMASK) << DBITS) | (unsigned)(d & DMASK);
            dest[sl] = gba[b] + sl;
        }
    __syncthreads();
    for (int t = tid; t < len; t += blockDim.x)
        packed[dest[t]] = sbuf[t];
}

// ---------------- aggregations ----------------

// deg: unchanged (no gathers) — the control kernel
__global__ __launch_bounds__(1024, 8)
void k_deg(const unsigned* __restrict__ packed, const int* __restrict__ rbase,
           const int* __restrict__ rlenp, int* __restrict__ pdeg, int n) {
    __shared__ int acc[DMASK + 1];   // 16 KB
    int r = blockIdx.y, b = blockIdx.x;
    int rs_r = min(DMASK + 1, n - (r << DBITS));
    for (int t = threadIdx.x; t < rs_r; t += blockDim.x) acc[t] = 0;
    __syncthreads();
    int base = rbase[r], q = rlenp[r] >> 2;
    int qper = (q + gridDim.x - 1) / gridDim.x;
    int qlo = b * qper, qhi = min(qlo + qper, q);
    const uint4* p4 = (const uint4*)(packed + base);
    for (int j = qlo + threadIdx.x; j < qhi; j += blockDim.x) {
        uint4 v = p4[j];
        if (v.x != NOEDGE) atomicAdd(&acc[v.x & DMASK], 1);
        if (v.y != NOEDGE) atomicAdd(&acc[v.y & DMASK], 1);
        if (v.z != NOEDGE) atomicAdd(&acc[v.z & DMASK], 1);
        if (v.w != NOEDGE) atomicAdd(&acc[v.w & DMASK], 1);
    }
    __syncthreads();
    int nb = b * n + (r << DBITS);
    for (int t = threadIdx.x; t < rs_r; t += blockDim.x) pdeg[nb + t] = acc[t];
}

// agg1: iterate bins of the block's contiguous span; stage px window in LDS;
// gathers become LDS reads.
__global__ __launch_bounds__(1024, 2)
void k_agg1(const unsigned* __restrict__ packed, const int* __restrict__ gbin,
            const int* __restrict__ rbase, const int* __restrict__ rlenp,
            const float2* __restrict__ px, float2* __restrict__ pP,
            int n, int NS) {
    __shared__ float acc[2 * (DMASK + 1)];   // 32 KB
    __shared__ float2 win[SMASK + 1];        // 16 KB
    __shared__ int gb[64];
    int r = blockIdx.y, b = blockIdx.x, tid = threadIdx.x;
    int rs_r = min(DMASK + 1, n - (r << DBITS));
    for (int t = tid; t < 2 * rs_r; t += blockDim.x) acc[t] = 0.f;
    int rb = rbase[r], rl = rlenp[r];
    if (tid <= NS) gb[tid] = (tid == NS) ? rb + rl : gbin[r * NS + tid];
    __syncthreads();
    int q = rl >> 2;
    int qper = (q + gridDim.x - 1) / gridDim.x;
    int qlo = min(b * qper, q), qhi = min(qlo + qper, q);
    int e0 = rb + qlo * 4, e1 = rb + qhi * 4;
    int k0 = 0;
    while (k0 + 1 < NS && gb[k0 + 1] <= e0) ++k0;
    for (int k = k0; k < NS && gb[k] < e1; ++k) {
        int lo = max(gb[k], e0), hi = min(gb[k + 1], e1);
        if (lo >= hi) continue;
        int wb = k << SBITS;
        int wlen = min(SMASK + 1, n - wb);
        for (int t = tid; t < wlen; t += blockDim.x) win[t] = px[wb + t];
        __syncthreads();
        const uint4* p4 = (const uint4*)(packed + lo);
        int nq = (hi - lo) >> 2;
        for (int j = tid; j < nq; j += blockDim.x) {
            uint4 v = p4[j];
            float2 g0 = win[(v.x >> DBITS) & SMASK];
            float2 g1 = win[(v.y >> DBITS) & SMASK];
            float2 g2 = win[(v.z >> DBITS) & SMASK];
            float2 g3 = win[(v.w >> DBITS) & SMASK];
            if (v.x != NOEDGE) { int d0 = (v.x & DMASK) * 2; atomicAdd(&acc[d0], g0.x); atomicAdd(&acc[d0 + 1], g0.y); }
            if (v.y != NOEDGE) { int d1 = (v.y & DMASK) * 2; atomicAdd(&acc[d1], g1.x); atomicAdd(&acc[d1 + 1], g1.y); }
            if (v.z != NOEDGE) { int d2 = (v.z & DMASK) * 2; atomicAdd(&acc[d2], g2.x); atomicAdd(&acc[d2 + 1], g2.y); }
            if (v.w != NOEDGE) { int d3 = (v.w & DMASK) * 2; atomicAdd(&acc[d3], g3.x); atomicAdd(&acc[d3 + 1], g3.y); }
        }
        __syncthreads();
    }
    int nb = b * n + (r << DBITS);
    for (int t = tid; t < rs_r; t += blockDim.x)
        pP[nb + t] = make_float2(acc[2 * t], acc[2 * t + 1]);
}

// agg2: same structure; window of scalar s.
__global__ __launch_bounds__(1024, 4)
void k_agg2(const unsigned* __restrict__ packed, const int* __restrict__ gbin,
            const int* __restrict__ rbase, const int* __restrict__ rlenp,
            const float* __restrict__ s, float* __restrict__ ps,
            int n, int NS) {
    __shared__ float acc[DMASK + 1];   // 16 KB
    __shared__ float win[SMASK + 1];   // 8 KB
    __shared__ int gb[64];
    int r = blockIdx.y, b = blockIdx.x, tid = threadIdx.x;
    int rs_r = min(DMASK + 1, n - (r << DBITS));
    for (int t = tid; t < rs_r; t += blockDim.x) acc[t] = 0.f;
    int rb = rbase[r], rl = rlenp[r];
    if (tid <= NS) gb[tid] = (tid == NS) ? rb + rl : gbin[r * NS + tid];
    __syncthreads();
    int q = rl >> 2;
    int qper = (q + gridDim.x - 1) / gridDim.x;
    int qlo = min(b * qper, q), qhi = min(qlo + qper, q);
    int e0 = rb + qlo * 4, e1 = rb + qhi * 4;
    int k0 = 0;
    while (k0 + 1 < NS && gb[k0 + 1] <= e0) ++k0;
    for (int k = k0; k < NS && gb[k] < e1; ++k) {
        int lo = max(gb[k], e0), hi = min(gb[k + 1], e1);
        if (lo >= hi) continue;
        int wb = k << SBITS;
        int wlen = min(SMASK + 1, n - wb);
        for (int t = tid; t < wlen; t += blockDim.x) win[t] = s[wb + t];
        __syncthreads();
        const uint4* p4 = (const uint4*)(packed + lo);
        int nq = (hi - lo) >> 2;
        for (int j = tid; j < nq; j += blockDim.x) {
            uint4 v = p4[j];
            float g0 = win[(v.x >> DBITS) & SMASK];
            float g1 = win[(v.y >> DBITS) & SMASK];
            float g2 = win[(v.z >> DBITS) & SMASK];
            float g3 = win[(v.w >> DBITS) & SMASK];
            if (v.x != NOEDGE) atomicAdd(&acc[v.x & DMASK], g0);
            if (v.y != NOEDGE) atomicAdd(&acc[v.y & DMASK], g1);
            if (v.z != NOEDGE) atomicAdd(&acc[v.z & DMASK], g2);
            if (v.w != NOEDGE) atomicAdd(&acc[v.w & DMASK], g3);
        }
        __syncthreads();
    }
    int nb = b * n + (r << DBITS);
    for (int t = tid; t < rs_r; t += blockDim.x) ps[nb + t] = acc[t];
}

// ---------------- fallback path (round-2 style) ----------------

__global__ void f_zero(int* __restrict__ ideg, float2* __restrict__ P, int n) {
    int i = blockIdx.x * blockDim.x + threadIdx.x;
    if (i < n) { ideg[i] = 0; P[i] = make_float2(0.f, 0.f); }
}
__global__ void f_count(const int* __restrict__ dst, int* __restrict__ ideg, int e) {
    int i = blockIdx.x * blockDim.x + threadIdx.x;
    if (i < e) atomicAdd(&ideg[dst[i]], 1);
}
__global__ void f_px(const float2* __restrict__ x, const int* __restrict__ ideg,
                     float* __restrict__ dinv, float2* __restrict__ px, int n) {
    int i = blockIdx.x * blockDim.x + threadIdx.x;
    if (i >= n) return;
    float d = rsqrtf((float)(1 + ideg[i]));
    dinv[i] = d;
    float2 xv = x[i];
    px[i] = make_float2(d * xv.x, d * xv.y);
}
__global__ void f_scatter_px(const int* __restrict__ src, const int* __restrict__ dst,
                             const float2* __restrict__ px, float* __restrict__ Pf, int e) {
    int i = blockIdx.x * blockDim.x + threadIdx.x;
    if (i >= e) return;
    int sidx = src[i], d = dst[i];
    float2 v = px[sidx];
    atomicAdd(&Pf[2 * d], v.x);
    atomicAdd(&Pf[2 * d + 1], v.y);
}
__global__ void f_node(const float2* __restrict__ px, const float2* __restrict__ P,
                       const float* __restrict__ dinv,
                       const float* __restrict__ W1, const float* __restrict__ b1,
                       const float* __restrict__ W2,
                       float* __restrict__ s, float* __restrict__ S, int n) {
    int i = blockIdx.x * blockDim.x + threadIdx.x;
    if (i >= n) return;
    float d = dinv[i];
    float2 v = px[i], p = P[i];
    float ax = v.x + p.x, ay = v.y + p.y;
    float dot = 0.f;
#pragma unroll
    for (int j = 0; j < 32; ++j) {
        float acc = fmaf(ax, W1[j], ay * W1[32 + j]);
        float h = fmaxf(fmaf(d, acc, b1[j]), 0.f);
        dot = fmaf(h, W2[j], dot);
    }
    float sv = d * dot;
    s[i] = sv;
    S[i] = sv;
}
__global__ void f_scatter_s(const int* __restrict__ src, const int* __restrict__ dst,
                            const float* __restrict__ s, float* __restrict__ S, int e) {
    int i = blockIdx.x * blockDim.x + threadIdx.x;
    if (i < e) atomicAdd(&S[dst[i]], s[src[i]]);
}
__global__ void f_out(const float* __restrict__ S, const float* __restrict__ dinv,
                      const float* __restrict__ b2, float* __restrict__ out, int n) {
    int i = blockIdx.x * blockDim.x + threadIdx.x;
    if (i < n) out[i] = dinv[i] * S[i] + b2[0];
}

// ---------------- launch ----------------

extern "C" void kernel_launch(void* const* d_in, const int* in_sizes, int n_in,
                              void* d_out, int out_size, void* d_ws, size_t ws_size,
                              hipStream_t stream) {
    const float* x  = (const float*)d_in[0];
    const int*   ei = (const int*)d_in[1];
    const float* W1 = (const float*)d_in[2];
    const float* b1 = (const float*)d_in[3];
    const float* W2 = (const float*)d_in[4];
    const float* b2 = (const float*)d_in[5];
    float* out = (float*)d_out;

    int n = in_sizes[0] / 2;   // 100000
    int e = in_sizes[1] / 2;   // 2560000
    const int* src = ei;
    const int* dst = ei + e;
    int NR  = (n + DMASK) >> DBITS;          // 25
    int NS  = (n + SMASK) >> SBITS;          // 49 src-windows of 2048
    int NB  = NR * NS;                       // 1225 bins
    int NCH = (e + CHUNK - 1) / CHUNK;       // 625 chunks

    char* ws = (char*)d_ws;
    auto align = [](size_t v) { return (v + 255) & ~(size_t)255; };
    size_t off = 0;
    float*  dinv = (float*) (ws + off); off = align(off + (size_t)n * 4);
    float2* px   = (float2*)(ws + off); off = align(off + (size_t)n * 8);
    float*  s    = (float*) (ws + off); off = align(off + (size_t)n * 4);
    int*    pdeg = (int*)   (ws + off); off = align(off + (size_t)AGG_BLKS * n * 4);
    float2* pP   = (float2*)(ws + off); off = align(off + (size_t)AGG_BLKS * n * 8);
    float*  ps   = (float*) (ws + off); off = align(off + (size_t)AGG_BLKS * n * 4);
    int*    rbase = (int*)(ws + off); off = align(off + NRMAX * 4);
    int*    rlenp = (int*)(ws + off); off = align(off + NRMAX * 4);
    int*    gbin  = (int*)(ws + off); off = align(off + 2048 * 4);
    int*    tot   = (int*)(ws + off); off = align(off + 2048 * 4);
    int*    cntT  = (int*)(ws + off); off = align(off + (size_t)NCHP * CSTR * 4);
    unsigned* packed = (unsigned*)(ws + off);
    size_t need = off + (size_t)(e + 4 * CSTR) * 4;

    const int B = 256;
    int gn = (n + B - 1) / B, ge = (e + B - 1) / B;

    bool fast = (need <= ws_size) && (NB <= CSTR) && (NCH <= NCHP) &&
                (NR <= NRMAX) && (NS <= 63);

    if (fast) {
        dim3 ag(AGG_BLKS, NR);
        k_cnt     <<<NCH, B, 0, stream>>>(src, dst, cntT, e, NS, NB);
        k_scanA   <<<NB, 1024, 0, stream>>>(cntT, tot, NCH);
        k_scanB   <<<1, 1024, 0, stream>>>(tot, gbin, rbase, rlenp, packed, NB, NS, NR);
        k_bscatter<<<NCH, 1024, 0, stream>>>(src, dst, cntT, tot, gbin, packed, e, NS, NB, NCH);
        k_deg     <<<ag, 1024, 0, stream>>>(packed, rbase, rlenp, pdeg, n);
        k_px      <<<gn, B, 0, stream>>>((const float2*)x, pdeg, dinv, px, n);
        k_agg1    <<<ag, 1024, 0, stream>>>(packed, gbin, rbase, rlenp, px, pP, n, NS);
        k_node    <<<gn, B, 0, stream>>>(px, pP, dinv, W1, b1, W2, s, n);
        k_agg2    <<<ag, 1024, 0, stream>>>(packed, gbin, rbase, rlenp, s, ps, n, NS);
        k_out     <<<gn, B, 0, stream>>>(s, ps, dinv, b2, out, n);
    } else {
        int*   ideg = pdeg;
        float2* P   = pP;
        float* S    = ps;
        f_zero      <<<gn, B, 0, stream>>>(ideg, P, n);
        f_count     <<<ge, B, 0, stream>>>(dst, ideg, e);
        f_px        <<<gn, B, 0, stream>>>((const float2*)x, ideg, dinv, px, n);
        f_scatter_px<<<ge, B, 0, stream>>>(src, dst, px, (float*)P, e);
        f_node      <<<gn, B, 0, stream>>>(px, P, dinv, W1, b1, W2, s, S, n);
        f_scatter_s <<<ge, B, 0, stream>>>(src, dst, s, S, e);
        f_out       <<<gn, B, 0, stream>>>(S, dinv, b2, out, n);
    }
}